// Round 1
// 403.843 us; speedup vs baseline: 1.0472x; 1.0472x over previous
//
#include <hip/hip_runtime.h>
#include <math.h>

// Problem constants (fixed by the reference)
#define NB 32       // batch
#define ND 1024     // CTX_DIM
#define NC 2048     // CTX_SIZE
#define NH 1024     // HID
#define NSEQ 64     // seqlen
#define CCHUNK 32   // c-tile width per block (32 c = 128 B rows: full lines)
#define NCHUNK (NC / CCHUNK)   // 64 chunks per batch

// ---------------------------------------------------------------------------
// k1: v[b,d] = sum_h hidden[b,h] * W[h,d]   (bias is softmax-invariant: dropped)
// 2-way h-split per block (256 threads) doubles latency hiding vs 128-thread
// version: 4 waves/CU issuing L2 reads of W instead of 2.
// grid = 32 b * 8 dchunks(128) = 256 blocks. W is L2-resident (4 MiB).
// ---------------------------------------------------------------------------
__global__ __launch_bounds__(256) void k1_v(const float* __restrict__ hidden,
                                            const float* __restrict__ W,
                                            float* __restrict__ v) {
  __shared__ float part[128];
  const int b = blockIdx.x >> 3;
  const int dl = threadIdx.x & 127;
  const int d = ((blockIdx.x & 7) << 7) + dl;
  const int hh = threadIdx.x >> 7;           // 0: h<512, 1: h>=512
  const float* hb = hidden + b * NH + hh * 512;
  const float* Wp = W + (size_t)hh * 512 * ND + d;
  float acc = 0.f;
#pragma unroll 16
  for (int h = 0; h < 512; ++h) acc += hb[h] * Wp[(size_t)h * ND];
  if (hh) part[dl] = acc;
  __syncthreads();
  if (!hh) v[b * ND + d] = acc + part[dl];
}

// ---------------------------------------------------------------------------
// k2: fused scores + chunk-local softmax + weighted partial sums.
// REGISTER-RESIDENT tile: each thread holds its 64 ctx floats (16 x float4,
// 64 VGPR) across the softmax barrier; both passes (scores, weighted sum)
// read registers instead of a 128 KB LDS tile. LDS drops to 8.3 KB ->
// 2 blocks/CU (launch_bounds caps VGPR at 128), so one block's global loads
// overlap the other block's compute: no barrier-drain HBM dead time.
// Thread map: t = dp*8 + cg; covers d = dp + 64*j (j=0..15), c = c0+4*cg..+3.
// Wave loads = 8 rows x 128 B aligned segments per instruction.
// Outputs: accp[bid][d] = sum_c exp(s_c - m)*ctx[b,d,c];  ml[bid] = {m, l}
// ---------------------------------------------------------------------------
__global__ __launch_bounds__(512, 4) void k2_main(const float* __restrict__ ctx,
                                                  const float* __restrict__ v,
                                                  float* __restrict__ accp,
                                                  float* __restrict__ ml) {
  __shared__ __align__(16) float sred[64 * 32];  // [dp][c] score partials, 8 KB
  __shared__ float pf[CCHUNK];                   // softmax weights

  const int t = threadIdx.x;           // 0..511
  const int bid = blockIdx.x;
  const int b = bid >> 6;              // / NCHUNK
  const int c0 = (bid & (NCHUNK - 1)) << 5;
  const int dp = t >> 3;               // 0..63  (d = dp + 64*j)
  const int cg = t & 7;                // c-group of 4 (8 groups = 32 c)

  // --- issue all 16 tile loads into registers (independent, pipelined)
  const float* g = ctx + (size_t)b * ND * NC + (size_t)dp * NC + c0 + (cg << 2);
  float4 x[16];
#pragma unroll
  for (int j = 0; j < 16; ++j) x[j] = *(const float4*)(g + (size_t)j * (64 * NC));

  // v fragments straight from global (L2-hot, 8-lane broadcast)
  float vsr[16];
  const float* vb = v + b * ND + dp;
#pragma unroll
  for (int j = 0; j < 16; ++j) vsr[j] = vb[j * 64];

  // --- Phase B: score partials from registers
  float4 s4 = make_float4(0.f, 0.f, 0.f, 0.f);
#pragma unroll
  for (int j = 0; j < 16; ++j) {
    const float vd = vsr[j];
    s4.x += x[j].x * vd; s4.y += x[j].y * vd;
    s4.z += x[j].z * vd; s4.w += x[j].w * vd;
  }
  *(float4*)(sred + 4 * t) = s4;   // sred[dp][cg*4 .. cg*4+3]
  __syncthreads();

  // --- chunk-local softmax over 32 c's (lanes 0..31: bank = c, conflict-free)
  if (t < 32) {
    float s = 0.f;
#pragma unroll
    for (int q = 0; q < 64; ++q) s += sred[32 * q + t];
    float mm = s;
#pragma unroll
    for (int off = 16; off; off >>= 1) mm = fmaxf(mm, __shfl_xor(mm, off, 32));
    float e = __expf(s - mm);
    float l = e;
#pragma unroll
    for (int off = 16; off; off >>= 1) l += __shfl_xor(l, off, 32);
    pf[t] = e;
    if (t == 0) { ml[bid * 2] = mm; ml[bid * 2 + 1] = l; }
  }
  __syncthreads();

  // --- Phase C: acc[d] = sum_c p[c] * x, from registers.
  // Each thread dots its 4 c's, then butterfly over the 8 cg lanes (same
  // wave: lane bits 0..2). All 8 lanes end with the full 32-c sum; the lane
  // with cg == (j&7) stores d = dp + 64*j (8 consecutive dp -> 32 B/wave).
  const float4 p4 = *(const float4*)(pf + (cg << 2));
  float* ao = accp + (size_t)bid * ND;
#pragma unroll
  for (int j = 0; j < 16; ++j) {
    float aj = x[j].x * p4.x + x[j].y * p4.y + x[j].z * p4.z + x[j].w * p4.w;
    aj += __shfl_xor(aj, 1, 64);
    aj += __shfl_xor(aj, 2, 64);
    aj += __shfl_xor(aj, 4, 64);
    if (cg == (j & 7)) ao[dp + (j << 6)] = aj;
  }
}

// ---------------------------------------------------------------------------
// k3: online-softmax combine across 64 chunks + broadcast to out[s,b,d].
// grid = 32 b * 8 d-slices(128) = 256 blocks, 128 threads.
// ---------------------------------------------------------------------------
__global__ __launch_bounds__(128) void k3_combine_bcast(
    const float* __restrict__ accp, const float* __restrict__ ml,
    float* __restrict__ out) {
  __shared__ float sc[NCHUNK];
  __shared__ float sinv_s;
  const int b = blockIdx.x >> 3;
  const int dslice = blockIdx.x & 7;
  const int t = threadIdx.x;           // 0..127

  if (t < NCHUNK) {                    // one wave does the combine math
    float mi = ml[(b * NCHUNK + t) * 2];
    float li = ml[(b * NCHUNK + t) * 2 + 1];
    float mg = mi;
#pragma unroll
    for (int off = 32; off; off >>= 1) mg = fmaxf(mg, __shfl_xor(mg, off, 64));
    float scale = __expf(mi - mg);
    float dpart = scale * li;
#pragma unroll
    for (int off = 32; off; off >>= 1) dpart += __shfl_xor(dpart, off, 64);
    sc[t] = scale;
    if (t == 0) sinv_s = 1.0f / dpart;
  }
  __syncthreads();
  const float sinv = sinv_s;

  const int d = dslice * 128 + t;
  const float* ap = accp + (size_t)b * NCHUNK * ND + d;
  float acc = 0.f;
#pragma unroll 16
  for (int i = 0; i < NCHUNK; ++i) acc += sc[i] * ap[(size_t)i * ND];
  acc *= sinv;

  float* op = out + b * ND + d;
#pragma unroll 8
  for (int s = 0; s < NSEQ; ++s) op[(size_t)s * NB * ND] = acc;
}

extern "C" void kernel_launch(void* const* d_in, const int* in_sizes, int n_in,
                              void* d_out, int out_size, void* d_ws, size_t ws_size,
                              hipStream_t stream) {
  (void)in_sizes; (void)n_in; (void)out_size; (void)ws_size;
  // d_in: [0]=seqlen(int,1) [1]=hidden(1,32,1024) [2]=contextvects(32,1024,2048)
  //       [3]=W(1024,1024) [4]=b(1024)  -- bias unused (softmax-invariant).
  const float* hidden = (const float*)d_in[1];
  const float* ctxv   = (const float*)d_in[2];
  const float* W      = (const float*)d_in[3];
  float* out = (float*)d_out;

  char* ws = (char*)d_ws;
  float* v    = (float*)(ws);                    // 32*1024 fp32   = 128 KB
  float* ml   = (float*)(ws + 131072);           // 2048*2 fp32    =  16 KB
  float* accp = (float*)(ws + 131072 + 16384);   // 2048*1024 fp32 =   8 MB

  k1_v<<<256, 256, 0, stream>>>(hidden, W, v);
  k2_main<<<NB * NCHUNK, 512, 0, stream>>>(ctxv, v, accp, ml);
  k3_combine_bcast<<<256, 128, 0, stream>>>(accp, ml, out);
}

// Round 2
// 372.817 us; speedup vs baseline: 1.1343x; 1.0832x over previous
//
#include <hip/hip_runtime.h>
#include <math.h>

// Problem constants (fixed by the reference)
#define NB 32       // batch
#define ND 1024     // CTX_DIM
#define NC 2048     // CTX_SIZE
#define NH 1024     // HID
#define NSEQ 64     // seqlen
#define CCHUNK 32   // c-tile width per block (32 c = 128 B rows: full lines)
#define NCHUNK (NC / CCHUNK)   // 64 chunks per batch

typedef float v4f __attribute__((ext_vector_type(4)));

// ---------------------------------------------------------------------------
// k1: v[b,d] = sum_h hidden[b,h] * W[h,d]   (bias is softmax-invariant: dropped)
// 4-way h-split per block (512 threads): 8 waves/CU, 128-deep reduction per
// thread -> half the exposed L2 latency of the 256-thread/2-way version.
// grid = 32 b * 8 dchunks(128) = 256 blocks. W slice per dchunk (512 KB) is
// L2-resident; dchunk == bid&7 == XCD under round-robin, so all 32 b-blocks
// reading the same W columns share one XCD's L2.
// ---------------------------------------------------------------------------
__global__ __launch_bounds__(512) void k1_v(const float* __restrict__ hidden,
                                            const float* __restrict__ W,
                                            float* __restrict__ v) {
  __shared__ float part[3][128];
  const int b = blockIdx.x >> 3;
  const int dl = threadIdx.x & 127;
  const int d = ((blockIdx.x & 7) << 7) + dl;
  const int hh = threadIdx.x >> 7;           // 0..3, h-quarter
  const float* hb = hidden + b * NH + hh * 256;
  const float* Wp = W + (size_t)(hh * 256) * ND + d;
  float acc = 0.f;
#pragma unroll 16
  for (int h = 0; h < 256; ++h) acc += hb[h] * Wp[(size_t)h * ND];
  if (hh) part[hh - 1][dl] = acc;
  __syncthreads();
  if (!hh) v[b * ND + d] = acc + part[0][dl] + part[1][dl] + part[2][dl];
}

// ---------------------------------------------------------------------------
// k2: fused scores + chunk-local softmax + weighted partial sums.
// REGISTER-RESIDENT tile: each thread holds its 64 ctx floats (16 x v4f,
// 64 VGPR) across the softmax barrier; both passes (scores, weighted sum)
// read registers. LDS = 8.3 KB -> 2 blocks/CU (launch_bounds caps VGPR at
// 128), so one block's global loads overlap the other block's compute.
// ctx loads are NONTEMPORAL: 256 MB streamed exactly once; keep it out of
// L2 so v (read 2048x) and accp (read back by k3) stay resident.
// Thread map: t = dp*8 + cg; covers d = dp + 64*j (j=0..15), c = c0+4*cg..+3.
// Outputs: accp[bid][d] = sum_c exp(s_c - m)*ctx[b,d,c];  ml[bid] = {m, l}
// ---------------------------------------------------------------------------
__global__ __launch_bounds__(512, 4) void k2_main(const float* __restrict__ ctx,
                                                  const float* __restrict__ v,
                                                  float* __restrict__ accp,
                                                  float* __restrict__ ml) {
  __shared__ __align__(16) float sred[64 * 32];  // [dp][c] score partials, 8 KB
  __shared__ float pf[CCHUNK];                   // softmax weights

  const int t = threadIdx.x;           // 0..511
  const int bid = blockIdx.x;
  const int b = bid >> 6;              // / NCHUNK
  const int c0 = (bid & (NCHUNK - 1)) << 5;
  const int dp = t >> 3;               // 0..63  (d = dp + 64*j)
  const int cg = t & 7;                // c-group of 4 (8 groups = 32 c)

  // --- issue all 16 tile loads into registers (independent, pipelined, NT)
  const float* g = ctx + (size_t)b * ND * NC + (size_t)dp * NC + c0 + (cg << 2);
  v4f x[16];
#pragma unroll
  for (int j = 0; j < 16; ++j)
    x[j] = __builtin_nontemporal_load((const v4f*)(g + (size_t)j * (64 * NC)));

  // v fragments straight from global (L2-hot, 8-lane broadcast)
  float vsr[16];
  const float* vb = v + b * ND + dp;
#pragma unroll
  for (int j = 0; j < 16; ++j) vsr[j] = vb[j * 64];

  // --- Phase B: score partials from registers
  v4f s4 = (v4f)(0.f);
#pragma unroll
  for (int j = 0; j < 16; ++j) s4 += x[j] * vsr[j];
  *(v4f*)(sred + 4 * t) = s4;   // sred[dp][cg*4 .. cg*4+3]
  __syncthreads();

  // --- chunk-local softmax over 32 c's (lanes 0..31: bank = c, conflict-free)
  if (t < 32) {
    float s = 0.f;
#pragma unroll
    for (int q = 0; q < 64; ++q) s += sred[32 * q + t];
    float mm = s;
#pragma unroll
    for (int off = 16; off; off >>= 1) mm = fmaxf(mm, __shfl_xor(mm, off, 32));
    float e = __expf(s - mm);
    float l = e;
#pragma unroll
    for (int off = 16; off; off >>= 1) l += __shfl_xor(l, off, 32);
    pf[t] = e;
    if (t == 0) { ml[bid * 2] = mm; ml[bid * 2 + 1] = l; }
  }
  __syncthreads();

  // --- Phase C: acc[d] = sum_c p[c] * x, from registers.
  // Each thread dots its 4 c's, then butterfly over the 8 cg lanes (lane
  // bits 0..2). The lane with cg == (j&7) stores d = dp + 64*j.
  const v4f p4 = *(const v4f*)(pf + (cg << 2));
  float* ao = accp + (size_t)bid * ND;
#pragma unroll
  for (int j = 0; j < 16; ++j) {
    v4f m4 = x[j] * p4;
    float aj = m4.x + m4.y + m4.z + m4.w;
    aj += __shfl_xor(aj, 1, 64);
    aj += __shfl_xor(aj, 2, 64);
    aj += __shfl_xor(aj, 4, 64);
    if (cg == (j & 7)) ao[dp + (j << 6)] = aj;
  }
}

// ---------------------------------------------------------------------------
// k3: online-softmax combine across 64 chunks + broadcast to out[s,b,d].
// grid = 32 b * 8 d-slices(128) * 2 s-halves = 512 blocks, 128 threads.
// Combine math is recomputed per block (trivial); out stores nontemporal
// (never re-read).
// ---------------------------------------------------------------------------
__global__ __launch_bounds__(128) void k3_combine_bcast(
    const float* __restrict__ accp, const float* __restrict__ ml,
    float* __restrict__ out) {
  __shared__ float sc[NCHUNK];
  __shared__ float sinv_s;
  const int b = blockIdx.x >> 4;
  const int dslice = (blockIdx.x >> 1) & 7;
  const int shalf = blockIdx.x & 1;
  const int t = threadIdx.x;           // 0..127

  if (t < NCHUNK) {                    // one wave does the combine math
    float mi = ml[(b * NCHUNK + t) * 2];
    float li = ml[(b * NCHUNK + t) * 2 + 1];
    float mg = mi;
#pragma unroll
    for (int off = 32; off; off >>= 1) mg = fmaxf(mg, __shfl_xor(mg, off, 64));
    float scale = __expf(mi - mg);
    float dpart = scale * li;
#pragma unroll
    for (int off = 32; off; off >>= 1) dpart += __shfl_xor(dpart, off, 64);
    sc[t] = scale;
    if (t == 0) sinv_s = 1.0f / dpart;
  }
  __syncthreads();
  const float sinv = sinv_s;

  const int d = dslice * 128 + t;
  const float* ap = accp + (size_t)b * NCHUNK * ND + d;
  float acc = 0.f;
#pragma unroll 16
  for (int i = 0; i < NCHUNK; ++i) acc += sc[i] * ap[(size_t)i * ND];
  acc *= sinv;

  float* op = out + b * ND + d + (size_t)shalf * (NSEQ / 2) * NB * ND;
#pragma unroll 8
  for (int s = 0; s < NSEQ / 2; ++s)
    __builtin_nontemporal_store(acc, op + (size_t)s * NB * ND);
}

extern "C" void kernel_launch(void* const* d_in, const int* in_sizes, int n_in,
                              void* d_out, int out_size, void* d_ws, size_t ws_size,
                              hipStream_t stream) {
  (void)in_sizes; (void)n_in; (void)out_size; (void)ws_size;
  // d_in: [0]=seqlen(int,1) [1]=hidden(1,32,1024) [2]=contextvects(32,1024,2048)
  //       [3]=W(1024,1024) [4]=b(1024)  -- bias unused (softmax-invariant).
  const float* hidden = (const float*)d_in[1];
  const float* ctxv   = (const float*)d_in[2];
  const float* W      = (const float*)d_in[3];
  float* out = (float*)d_out;

  char* ws = (char*)d_ws;
  float* v    = (float*)(ws);                    // 32*1024 fp32   = 128 KB
  float* ml   = (float*)(ws + 131072);           // 2048*2 fp32    =  16 KB
  float* accp = (float*)(ws + 131072 + 16384);   // 2048*1024 fp32 =   8 MB

  k1_v<<<256, 512, 0, stream>>>(hidden, W, v);
  k2_main<<<NB * NCHUNK, 512, 0, stream>>>(ctxv, v, accp, ml);
  k3_combine_bcast<<<512, 128, 0, stream>>>(accp, ml, out);
}